// Round 1
// baseline (1391.825 us; speedup 1.0000x reference)
//
#include <hip/hip_runtime.h>
#include <cstdint>
#include <cstddef>

// Swin block, MI355X. Round 1: correctness-first bf16-MFMA pipeline.
// Token layout: window-major t = ((b*1024 + wy*32 + wx)*64 + iy*8 + ix), M = 262144.

typedef unsigned short u16;
typedef unsigned int u32;
typedef short short8 __attribute__((ext_vector_type(8)));
typedef float f32x4 __attribute__((ext_vector_type(4)));
typedef int int4v __attribute__((ext_vector_type(4)));

#define LN_EPS 1e-5f
#define QSCALE 0.17677669529663689f
#define M_TOK 262144
#define NWIN 4096

static __device__ __forceinline__ u16 f2bf(float f) {
    u32 u = __builtin_bit_cast(u32, f);
    u += 0x7fffu + ((u >> 16) & 1u);
    return (u16)(u >> 16);
}
static __device__ __forceinline__ float bf2f(u16 h) {
    u32 u = ((u32)h) << 16;
    return __builtin_bit_cast(float, u);
}

__global__ __launch_bounds__(256) void castw_kernel(const float* __restrict__ src,
                                                    u16* __restrict__ dst, int n) {
    int i = blockIdx.x * 256 + threadIdx.x;
    if (i < n) dst[i] = f2bf(src[i]);
}

// Per-pixel LN1 stats. pix = b*65536 + h*256 + w. Coalesced: lane i -> pixel i.
__global__ __launch_bounds__(256) void ln_stats_kernel(const float* __restrict__ x,
                                                       float* __restrict__ mean,
                                                       float* __restrict__ rstd) {
    int pix = blockIdx.x * 256 + threadIdx.x;
    int b = pix >> 16;
    int p2 = pix & 65535;
    const float* xp = x + (((size_t)b * 192) << 16) + p2;
    float s = 0.f, ss = 0.f;
#pragma unroll 8
    for (int c = 0; c < 192; ++c) {
        float v = xp[(size_t)c << 16];
        s += v;
        ss += v * v;
    }
    float mu = s * (1.f / 192.f);
    float var = ss * (1.f / 192.f) - mu * mu;
    mean[pix] = mu;
    rstd[pix] = rsqrtf(var + LN_EPS);
}

// LN1 apply + transpose BCHW -> token-major bf16 [t][192]. Block = 192c x 32px strip.
__global__ __launch_bounds__(256) void ln1_apply_kernel(
        const float* __restrict__ x, const float* __restrict__ mean,
        const float* __restrict__ rstd, const float* __restrict__ gw,
        const float* __restrict__ gb, u16* __restrict__ xw) {
    __shared__ float tile[192 * 33];
    int bid = blockIdx.x;              // 4*256*8 = 8192
    int colb = (bid & 7) << 5;
    int row = (bid >> 3) & 255;
    int bimg = bid >> 11;
    int tid = threadIdx.x;
    const float* xbase = x + (((size_t)bimg * 192) << 16) + row * 256 + colb;
    for (int it = 0; it < 24; ++it) {
        int e = it * 256 + tid;
        int cc = e >> 5, p = e & 31;
        tile[cc * 33 + p] = xbase[((size_t)cc << 16) + p];
    }
    __syncthreads();
    int wy = row >> 3, iy = row & 7;
    int pixbase = (bimg << 16) + row * 256 + colb;
    for (int it = 0; it < 24; ++it) {
        int e = it * 256 + tid;
        int tloc = e / 192, cc = e - tloc * 192;
        int px = colb + tloc;
        int wx = px >> 3, ix = px & 7;
        int t = (((bimg << 10) + (wy << 5) + wx) << 6) + iy * 8 + ix;
        int pix = pixbase + tloc;
        float v = (tile[cc * 33 + tloc] - mean[pix]) * rstd[pix] * gw[cc] + gb[cc];
        xw[(size_t)t * 192 + cc] = f2bf(v);
    }
}

enum { EPI_QKV = 0, EPI_BF16 = 1, EPI_GELU = 2, EPI_OUT = 3 };

// C = A(bf16,[M][K]) * Bw(bf16,[N][K])^T. BM=128 BN=64 BK=64, 4 waves (2x2),
// each wave 64x32 = 4x2 tiles of 16x16x32 mfma. LDS rows padded to 72 bf16
// (144B stride: 16B-aligned b128, 2-way-bank-free).
template <int EPI>
__global__ __launch_bounds__(256) void gemm_kernel(
        const u16* __restrict__ A, const u16* __restrict__ Bw, int N, int K,
        const float* __restrict__ bias, u16* __restrict__ o_bf,
        u16* __restrict__ o_k, u16* __restrict__ o_v,
        const u16* __restrict__ resid, float* __restrict__ o_f32) {
    extern __shared__ char smem[];
    u16* a_lds = (u16*)smem;                    // [128][72]
    u16* b_lds = (u16*)(smem + 128 * 72 * 2);   // [64][72]
    int tid = threadIdx.x;
    int lane = tid & 63, wave = tid >> 6;
    int g = lane >> 4, c = lane & 15;
    int wm = wave >> 1, wn = wave & 1;
    int nbn = N >> 6;
    int bid = blockIdx.x;
    int m0 = (bid / nbn) << 7;
    int n0 = (bid % nbn) << 6;
    int chunk = tid & 7, rbase = tid >> 3;

    f32x4 acc[4][2];
#pragma unroll
    for (int i = 0; i < 4; ++i)
#pragma unroll
        for (int j = 0; j < 2; ++j) acc[i][j] = (f32x4){0.f, 0.f, 0.f, 0.f};

    for (int k0 = 0; k0 < K; k0 += 64) {
#pragma unroll
        for (int it = 0; it < 4; ++it) {
            int row = rbase + it * 32;
            int4v val = *(const int4v*)(A + (size_t)(m0 + row) * K + k0 + chunk * 8);
            *(int4v*)(a_lds + row * 72 + chunk * 8) = val;
        }
#pragma unroll
        for (int it = 0; it < 2; ++it) {
            int row = rbase + it * 32;
            int4v val = *(const int4v*)(Bw + (size_t)(n0 + row) * K + k0 + chunk * 8);
            *(int4v*)(b_lds + row * 72 + chunk * 8) = val;
        }
        __syncthreads();
#pragma unroll
        for (int s = 0; s < 2; ++s) {
            short8 af[4], bfr[2];
#pragma unroll
            for (int mt = 0; mt < 4; ++mt)
                af[mt] = *(const short8*)(a_lds + (wm * 64 + mt * 16 + c) * 72 + s * 32 + g * 8);
#pragma unroll
            for (int nt = 0; nt < 2; ++nt)
                bfr[nt] = *(const short8*)(b_lds + (wn * 32 + nt * 16 + c) * 72 + s * 32 + g * 8);
#pragma unroll
            for (int mt = 0; mt < 4; ++mt)
#pragma unroll
                for (int nt = 0; nt < 2; ++nt)
                    acc[mt][nt] = __builtin_amdgcn_mfma_f32_16x16x32_bf16(
                        af[mt], bfr[nt], acc[mt][nt], 0, 0, 0);
        }
        __syncthreads();
    }

    if constexpr (EPI == EPI_QKV) {
        // scatter to q/k/v [head][win][64][32]; q scaled (after bias, like ref)
#pragma unroll
        for (int mt = 0; mt < 4; ++mt)
#pragma unroll
            for (int nt = 0; nt < 2; ++nt) {
                int n = n0 + wn * 32 + nt * 16 + c;
                int part = n / 192;
                int rem = n - part * 192;
                int hh = rem >> 5, d = rem & 31;
                u16* dst = (part == 0) ? o_bf : ((part == 1) ? o_k : o_v);
                float bi = bias[n];
                float sc = (part == 0) ? QSCALE : 1.f;
#pragma unroll
                for (int r = 0; r < 4; ++r) {
                    int m = m0 + wm * 64 + mt * 16 + g * 4 + r;
                    float v = (acc[mt][nt][r] + bi) * sc;
                    int w = m >> 6, tl = m & 63;
                    dst[(((size_t)hh * NWIN + w) * 64 + tl) * 32 + d] = f2bf(v);
                }
            }
    } else if constexpr (EPI == EPI_BF16 || EPI == EPI_GELU) {
#pragma unroll
        for (int mt = 0; mt < 4; ++mt)
#pragma unroll
            for (int nt = 0; nt < 2; ++nt) {
                int n = n0 + wn * 32 + nt * 16 + c;
                float bi = bias[n];
#pragma unroll
                for (int r = 0; r < 4; ++r) {
                    int m = m0 + wm * 64 + mt * 16 + g * 4 + r;
                    float v = acc[mt][nt][r] + bi;
                    if constexpr (EPI == EPI_GELU)
                        v = 0.5f * v * (1.f + erff(v * 0.70710678118654752f));
                    o_bf[(size_t)m * N + n] = f2bf(v);
                }
            }
    } else {  // EPI_OUT: +bias +resid(xmid bf16) -> BCHW fp32 via LDS transpose
        float* ot = (float*)smem;  // [128][65]
#pragma unroll
        for (int mt = 0; mt < 4; ++mt)
#pragma unroll
            for (int nt = 0; nt < 2; ++nt) {
                int nl = wn * 32 + nt * 16 + c;
                int n = n0 + nl;
                float bi = bias[n];
#pragma unroll
                for (int r = 0; r < 4; ++r) {
                    int ml = wm * 64 + mt * 16 + g * 4 + r;
                    int m = m0 + ml;
                    float v = acc[mt][nt][r] + bi + bf2f(resid[(size_t)m * 192 + n]);
                    ot[ml * 65 + nl] = v;
                }
            }
        __syncthreads();
        int w0 = m0 >> 6;
        int b = w0 >> 10;
        int wy = (w0 & 1023) >> 5;
        int wx = w0 & 31;
#pragma unroll
        for (int it = 0; it < 4; ++it) {
            int pi = it * 256 + tid;
            int cl = pi & 63, wr = pi >> 6;
            int widx = wr >> 3, iy = wr & 7;
            f32x4 v0, v1;
#pragma unroll
            for (int ix = 0; ix < 4; ++ix) v0[ix] = ot[(wr * 8 + ix) * 65 + cl];
#pragma unroll
            for (int ix = 0; ix < 4; ++ix) v1[ix] = ot[(wr * 8 + 4 + ix) * 65 + cl];
            size_t base = (((size_t)b * 192 + n0 + cl) << 16) +
                          (size_t)(wy * 8 + iy) * 256 + (size_t)(wx + widx) * 8;
            *(f32x4*)(o_f32 + base) = v0;
            *(f32x4*)(o_f32 + base + 4) = v1;
        }
    }
}

// One wave per (head, window). S^T = mfma(K,Q) so softmax per output-row i
// reduces with 2 shfl_xor; P redistributed to PV B-frags via packed shuffles.
__global__ __launch_bounds__(64) void attn_kernel(const u16* __restrict__ qg,
                                                  const u16* __restrict__ kg,
                                                  const u16* __restrict__ vg,
                                                  u16* __restrict__ aout) {
    __shared__ u16 vt[32 * 72];
    int bid = blockIdx.x;  // h*4096 + w
    int h = bid >> 12;
    int w = bid & 4095;
    size_t base = (size_t)bid * 2048;
    int lane = threadIdx.x;
    int g = lane >> 4, c = lane & 15;

    // stage V^T
#pragma unroll
    for (int it = 0; it < 4; ++it) {
        int tok = it * 16 + (lane >> 2);
        int d0 = (lane & 3) * 8;
        short8 vv = *(const short8*)(vg + base + tok * 32 + d0);
#pragma unroll
        for (int j = 0; j < 8; ++j) vt[(d0 + j) * 72 + tok] = (u16)vv[j];
    }

    short8 kf[4], qf[4];
#pragma unroll
    for (int tj = 0; tj < 4; ++tj)
        kf[tj] = *(const short8*)(kg + base + (tj * 16 + c) * 32 + g * 8);
#pragma unroll
    for (int ti = 0; ti < 4; ++ti)
        qf[ti] = *(const short8*)(qg + base + (ti * 16 + c) * 32 + g * 8);

    f32x4 st[4][4];
#pragma unroll
    for (int tj = 0; tj < 4; ++tj)
#pragma unroll
        for (int ti = 0; ti < 4; ++ti) st[tj][ti] = (f32x4){0.f, 0.f, 0.f, 0.f};
#pragma unroll
    for (int tj = 0; tj < 4; ++tj)
#pragma unroll
        for (int ti = 0; ti < 4; ++ti)
            st[tj][ti] = __builtin_amdgcn_mfma_f32_16x16x32_bf16(kf[tj], qf[ti],
                                                                 st[tj][ti], 0, 0, 0);

    float inv_s[4];
    u32 pk[4][4][2];
#pragma unroll
    for (int ti = 0; ti < 4; ++ti) {
        float mx = -1e30f;
#pragma unroll
        for (int tj = 0; tj < 4; ++tj)
#pragma unroll
            for (int r = 0; r < 4; ++r) mx = fmaxf(mx, st[tj][ti][r]);
        mx = fmaxf(mx, __shfl_xor(mx, 16));
        mx = fmaxf(mx, __shfl_xor(mx, 32));
        float sum = 0.f;
#pragma unroll
        for (int tj = 0; tj < 4; ++tj)
#pragma unroll
            for (int r = 0; r < 4; ++r) {
                float e = __expf(st[tj][ti][r] - mx);
                st[tj][ti][r] = e;
                sum += e;
            }
        sum += __shfl_xor(sum, 16);
        sum += __shfl_xor(sum, 32);
        inv_s[ti] = 1.f / sum;
#pragma unroll
        for (int tj = 0; tj < 4; ++tj) {
            pk[tj][ti][0] = (u32)f2bf(st[tj][ti][0]) | ((u32)f2bf(st[tj][ti][1]) << 16);
            pk[tj][ti][1] = (u32)f2bf(st[tj][ti][2]) | ((u32)f2bf(st[tj][ti][3]) << 16);
        }
    }

    __syncthreads();
    short8 vf[2][2];
#pragma unroll
    for (int td = 0; td < 2; ++td)
#pragma unroll
        for (int s = 0; s < 2; ++s)
            vf[td][s] = *(const short8*)(vt + (td * 16 + c) * 72 + s * 32 + g * 8);

    f32x4 oacc[2][4];
#pragma unroll
    for (int td = 0; td < 2; ++td)
#pragma unroll
        for (int ti = 0; ti < 4; ++ti) oacc[td][ti] = (f32x4){0.f, 0.f, 0.f, 0.f};

#pragma unroll
    for (int s = 0; s < 2; ++s)
#pragma unroll
        for (int ti = 0; ti < 4; ++ti) {
            u32 bw[4];
#pragma unroll
            for (int q = 0; q < 4; ++q) {
                // receiver (g) needs B[k=s*32+8g+2q+{0,1}][i]; src lane group
                // gs = 2*(g&1)+(q>>1); value index tj = 2s+(g>>1) is receiver-
                // dependent, so shuffle both tj candidates and select.
                int gs = 2 * (g & 1) + (q >> 1);
                int src = gs * 16 + c;
                u32 a0 = (u32)__shfl((int)pk[2 * s][ti][q & 1], src);
                u32 a1 = (u32)__shfl((int)pk[2 * s + 1][ti][q & 1], src);
                bw[q] = (g >= 2) ? a1 : a0;
            }
            union { u32 u[4]; short8 s8; } cvt;
            cvt.u[0] = bw[0]; cvt.u[1] = bw[1]; cvt.u[2] = bw[2]; cvt.u[3] = bw[3];
#pragma unroll
            for (int td = 0; td < 2; ++td)
                oacc[td][ti] = __builtin_amdgcn_mfma_f32_16x16x32_bf16(
                    vf[td][s], cvt.s8, oacc[td][ti], 0, 0, 0);
        }

#pragma unroll
    for (int td = 0; td < 2; ++td)
#pragma unroll
        for (int ti = 0; ti < 4; ++ti) {
            float iv = inv_s[ti];
            u32 lo = (u32)f2bf(oacc[td][ti][0] * iv) | ((u32)f2bf(oacc[td][ti][1] * iv) << 16);
            u32 hi = (u32)f2bf(oacc[td][ti][2] * iv) | ((u32)f2bf(oacc[td][ti][3] * iv) << 16);
            size_t addr = ((size_t)(w * 64 + ti * 16 + c)) * 192 + h * 32 + td * 16 + g * 4;
            u32* p = (u32*)(aout + addr);
            p[0] = lo;
            p[1] = hi;
        }
}

// xmid = x + y (proj out); LN2 fused; writes xmid bf16 and xln2 bf16 (token-major).
__global__ __launch_bounds__(256) void resid_ln2_kernel(
        const float* __restrict__ x, const u16* __restrict__ y,
        const float* __restrict__ gw, const float* __restrict__ gb,
        u16* __restrict__ xmid, u16* __restrict__ xln2) {
    __shared__ float tile[192 * 33];
    __shared__ float xmt[32 * 193];
    __shared__ float lmu[32], lrs[32];
    int bid = blockIdx.x;
    int colb = (bid & 7) << 5;
    int row = (bid >> 3) & 255;
    int bimg = bid >> 11;
    int tid = threadIdx.x;
    const float* xbase = x + (((size_t)bimg * 192) << 16) + row * 256 + colb;
    for (int it = 0; it < 24; ++it) {
        int e = it * 256 + tid;
        int cc = e >> 5, p = e & 31;
        tile[cc * 33 + p] = xbase[((size_t)cc << 16) + p];
    }
    __syncthreads();
    int wy = row >> 3, iy = row & 7;
    for (int it = 0; it < 24; ++it) {
        int e = it * 256 + tid;
        int tloc = e / 192, cc = e - tloc * 192;
        int px = colb + tloc;
        int wx = px >> 3, ix = px & 7;
        int t = (((bimg << 10) + (wy << 5) + wx) << 6) + iy * 8 + ix;
        float v = tile[cc * 33 + tloc] + bf2f(y[(size_t)t * 192 + cc]);
        xmid[(size_t)t * 192 + cc] = f2bf(v);
        xmt[tloc * 193 + cc] = v;
    }
    __syncthreads();
    {
        int tloc = tid >> 3, part = tid & 7;
        float s = 0.f, ss = 0.f;
#pragma unroll
        for (int j = 0; j < 24; ++j) {
            float v = xmt[tloc * 193 + part * 24 + j];
            s += v;
            ss += v * v;
        }
        s += __shfl_xor(s, 1); ss += __shfl_xor(ss, 1);
        s += __shfl_xor(s, 2); ss += __shfl_xor(ss, 2);
        s += __shfl_xor(s, 4); ss += __shfl_xor(ss, 4);
        if (part == 0) {
            float mu = s * (1.f / 192.f);
            float var = ss * (1.f / 192.f) - mu * mu;
            lmu[tloc] = mu;
            lrs[tloc] = rsqrtf(var + LN_EPS);
        }
    }
    __syncthreads();
    for (int it = 0; it < 24; ++it) {
        int e = it * 256 + tid;
        int tloc = e / 192, cc = e - tloc * 192;
        int px = colb + tloc;
        int wx = px >> 3, ix = px & 7;
        int t = (((bimg << 10) + (wy << 5) + wx) << 6) + iy * 8 + ix;
        float v = (xmt[tloc * 193 + cc] - lmu[tloc]) * lrs[tloc] * gw[cc] + gb[cc];
        xln2[(size_t)t * 192 + cc] = f2bf(v);
    }
}

extern "C" void kernel_launch(void* const* d_in, const int* in_sizes, int n_in,
                              void* d_out, int out_size, void* d_ws, size_t ws_size,
                              hipStream_t stream) {
    const float* x      = (const float*)d_in[0];
    const float* n1w    = (const float*)d_in[1];
    const float* n1b    = (const float*)d_in[2];
    const float* qkv_w  = (const float*)d_in[3];
    const float* qkv_b  = (const float*)d_in[4];
    const float* proj_w = (const float*)d_in[5];
    const float* proj_b = (const float*)d_in[6];
    const float* n2w    = (const float*)d_in[7];
    const float* n2b    = (const float*)d_in[8];
    const float* w1     = (const float*)d_in[9];
    const float* b1     = (const float*)d_in[10];
    const float* w2     = (const float*)d_in[11];
    const float* b2     = (const float*)d_in[12];
    float* out = (float*)d_out;

    char* ws = (char*)d_ws;
    size_t off = 0;
    auto alloc = [&](size_t bytes) {
        off = (off + 255) & ~(size_t)255;
        char* p = ws + off;
        off += bytes;
        return p;
    };
    u16* wqkv  = (u16*)alloc(110592 * 2);
    u16* wproj = (u16*)alloc(36864 * 2);
    u16* w1b   = (u16*)alloc(147456 * 2);
    u16* w2b   = (u16*)alloc(147456 * 2);
    float* mean1 = (float*)alloc((size_t)M_TOK * 4);
    float* rstd1 = (float*)alloc((size_t)M_TOK * 4);
    u16* xw   = (u16*)alloc((size_t)M_TOK * 192 * 2);
    u16* big  = (u16*)alloc((size_t)M_TOK * 768 * 2);  // q|k|v|attnout, later h1
    u16* xmid = (u16*)alloc((size_t)M_TOK * 192 * 2);
    if (off > ws_size) return;  // workspace too small -> clean fail

    u16* qg   = big;
    u16* kg   = big + (size_t)M_TOK * 192;
    u16* vg   = kg + (size_t)M_TOK * 192;
    u16* aout = vg + (size_t)M_TOK * 192;
    u16* ybuf = qg;   // reuse (q dead after attention)
    u16* xln2 = xw;   // reuse (xw dead after qkv gemm)
    u16* h1   = big;  // reuse (q/k/v/aout dead after proj)

    castw_kernel<<<(110592 + 255) / 256, 256, 0, stream>>>(qkv_w, wqkv, 110592);
    castw_kernel<<<(36864 + 255) / 256, 256, 0, stream>>>(proj_w, wproj, 36864);
    castw_kernel<<<(147456 + 255) / 256, 256, 0, stream>>>(w1, w1b, 147456);
    castw_kernel<<<(147456 + 255) / 256, 256, 0, stream>>>(w2, w2b, 147456);

    ln_stats_kernel<<<M_TOK / 256, 256, 0, stream>>>(x, mean1, rstd1);
    ln1_apply_kernel<<<8192, 256, 0, stream>>>(x, mean1, rstd1, n1w, n1b, xw);

    gemm_kernel<EPI_QKV><<<2048 * 9, 256, 27648, stream>>>(
        xw, wqkv, 576, 192, qkv_b, qg, kg, vg, nullptr, nullptr);

    attn_kernel<<<6 * NWIN, 64, 0, stream>>>(qg, kg, vg, aout);

    gemm_kernel<EPI_BF16><<<2048 * 3, 256, 27648, stream>>>(
        aout, wproj, 192, 192, proj_b, ybuf, nullptr, nullptr, nullptr, nullptr);

    resid_ln2_kernel<<<8192, 256, 0, stream>>>(x, ybuf, n2w, n2b, xmid, xln2);

    gemm_kernel<EPI_GELU><<<2048 * 12, 256, 27648, stream>>>(
        xln2, w1b, 768, 192, b1, h1, nullptr, nullptr, nullptr, nullptr);

    gemm_kernel<EPI_OUT><<<2048 * 3, 256, 33280, stream>>>(
        h1, w2b, 192, 768, b2, nullptr, nullptr, nullptr, xmid, out);
}